// Round 10
// baseline (957.853 us; speedup 1.0000x reference)
//
#include <hip/hip_runtime.h>
#include <hip/hip_bf16.h>

#define DIM 64
#define NCLS_OUT 40
#define BSH 8          // rows per bucket = 256
#define BROWS 256
#define BIN_CHUNK 12288

typedef __hip_bfloat16 bf16;

__device__ __forceinline__ float lane_bcast(float v, int l) {
  return __int_as_float(__builtin_amdgcn_readlane(__float_as_int(v), l));
}
__device__ __forceinline__ unsigned short f2bf_bits(float f) {
  bf16 h = __float2bfloat16(f);
  return *reinterpret_cast<unsigned short*>(&h);
}
__device__ __forceinline__ float bfbits2f(unsigned short u) {
  return __uint_as_float((unsigned)u << 16);
}

// mode: 1 = float inputs/outputs stored as f32, 0 = stored as bf16
__device__ __forceinline__ float ldf(const void* p, long i, int m) {
  return m ? ((const float*)p)[i] : __bfloat162float(((const bf16*)p)[i]);
}
__device__ __forceinline__ void stf(void* p, long i, float v, int m) {
  if (m) ((float*)p)[i] = v;
  else ((bf16*)p)[i] = __float2bfloat16(v);
}

// ---- dtype detector ----
__global__ void k_detect(const unsigned int* __restrict__ wds, int nw, int* __restrict__ mode) {
  __shared__ int cnt_s;
  if (threadIdx.x == 0) cnt_s = 0;
  __syncthreads();
  int c = 0;
  for (int i = threadIdx.x; i < nw; i += 1024) {
    unsigned h = wds[i] & 0xFFFFu;
    unsigned e = (h >> 7) & 0xFFu;
    if (e == 0xFFu || (e != 0u && e < 0x60u)) c++;
  }
  atomicAdd(&cnt_s, c);
  __syncthreads();
  if (threadIdx.x == 0) *mode = (cnt_s > nw / 16) ? 1 : 0;
}

// ---- dst bucket histogram only (LDS-staged; no per-edge global atomics) ----
__global__ void k_bh(const int* __restrict__ dst1, const int* __restrict__ dst2,
                     int* __restrict__ bh, int n, int e1, int etot, int NB) {
  extern __shared__ int cnt[];
  for (int b = threadIdx.x; b < NB; b += blockDim.x) cnt[b] = 0;
  __syncthreads();
  int stride = gridDim.x * blockDim.x;
  for (int i = blockIdx.x * blockDim.x + threadIdx.x; i < etot; i += stride) {
    int row = (i < e1) ? dst1[i] : (n + dst2[i - e1]);
    atomicAdd(&cnt[row >> BSH], 1);
  }
  __syncthreads();
  for (int b = threadIdx.x; b < NB; b += blockDim.x)
    if (cnt[b]) atomicAdd(&bh[b], cnt[b]);
}

// ---- scan bucket counts -> bucket bases (single block; NB is small) ----
__global__ void k_bscan(const int* __restrict__ bh, int* __restrict__ bbase,
                        int* __restrict__ gcur, int* __restrict__ rp,
                        int NB, int etot, int n2) {
  __shared__ int sm[256];
  __shared__ int carry_s;
  int t = threadIdx.x;
  if (t == 0) carry_s = 0;
  __syncthreads();
  for (int base = 0; base < NB; base += 256) {
    int i = base + t;
    int v = (i < NB) ? bh[i] : 0;
    sm[t] = v;
    __syncthreads();
    for (int o = 1; o < 256; o <<= 1) {
      int a = (t >= o) ? sm[t - o] : 0;
      __syncthreads();
      sm[t] += a;
      __syncthreads();
    }
    int c = carry_s;
    int excl = c + sm[t] - v;
    int tot = sm[255];
    __syncthreads();
    if (i < NB) { bbase[i] = excl; gcur[i] = excl; }
    if (t == 0) carry_s = c + tot;
    __syncthreads();
  }
  if (t == 0) { bbase[NB] = etot; rp[n2] = etot; }
}

// ---- binning scatter: edges -> bucket-grouped eb[] + out-degree atomics ----
// (out-degree atomics folded in here: this pass already touches every edge,
// so k_bh stays a pure dst-stream and the src arrays are read exactly once.)
__global__ void __launch_bounds__(256) k_bin(
    const int* __restrict__ src1, const int* __restrict__ dst1,
    const int* __restrict__ src2, const int* __restrict__ dst2,
    int* __restrict__ gcur, unsigned* __restrict__ eb, int* __restrict__ deg,
    int n, int e1, int etot, int NB) {
  extern __shared__ int lds[];
  int* cnt = lds;       // NB
  int* base = lds + NB; // NB
  int t = threadIdx.x;
  int c0 = blockIdx.x * BIN_CHUNK;
  int cend = c0 + BIN_CHUNK;
  if (cend > etot) cend = etot;
  for (int b = t; b < NB; b += 256) cnt[b] = 0;
  __syncthreads();
  for (int i = c0 + t; i < cend; i += 256) {
    int row = (i < e1) ? dst1[i] : (n + dst2[i - e1]);
    atomicAdd(&cnt[row >> BSH], 1);
  }
  __syncthreads();
  for (int b = t; b < NB; b += 256) {
    int c = cnt[b];
    base[b] = c ? atomicAdd(&gcur[b], c) : 0;
    cnt[b] = 0;  // reuse as local cursor
  }
  __syncthreads();
  for (int i = c0 + t; i < cend; i += 256) {
    int s, row, dgi;
    if (i < e1) { s = src1[i]; row = dst1[i]; dgi = s; }
    else { s = src2[i - e1]; row = n + dst2[i - e1]; dgi = n + s; }
    atomicAdd(&deg[2 * n + dgi], 1);
    int b = row >> BSH;
    int l = atomicAdd(&cnt[b], 1);
    eb[base[b] + l] = ((unsigned)(row & (BROWS - 1)) << 24) | (unsigned)s;
  }
}

// ---- fine fill: one block per bucket ----
// LDS histogram -> in-degree norms + rp (LDS scan) + sb scatter in the
// bucket's L2-resident slice. Also computes OUT norms for its row range
// (deg out-half is complete by now; out-half starts at deg[n2]).
__global__ void __launch_bounds__(256) k_fine(
    const unsigned* __restrict__ eb, const int* __restrict__ bbase,
    int* __restrict__ rp, const int* __restrict__ deg, float* __restrict__ nrm,
    int* __restrict__ sb, int n2, int NB) {
  __shared__ int hist[256];
  __shared__ int sm[256];
  __shared__ int curs[256];
  int t = threadIdx.x;
  for (int b = blockIdx.x; b < NB; b += gridDim.x) {
    int ebeg = bbase[b], eend = bbase[b + 1];
    hist[t] = 0;
    __syncthreads();
    for (int i = ebeg + t; i < eend; i += 256)
      atomicAdd(&hist[eb[i] >> 24], 1);
    __syncthreads();
    int v = hist[t];
    sm[t] = v;
    __syncthreads();
    for (int o = 1; o < 256; o <<= 1) {
      int a = (t >= o) ? sm[t - o] : 0;
      __syncthreads();
      sm[t] += a;
      __syncthreads();
    }
    int excl = sm[t] - v;
    int row = (b << BSH) + t;
    if (row < n2) {
      rp[row] = ebeg + excl;
      nrm[row] = rsqrtf((float)(v < 1 ? 1 : v));                 // in-norm
      int dov = deg[n2 + row];                                   // deg[2n+row]
      nrm[n2 + row] = rsqrtf((float)(dov < 1 ? 1 : dov));        // out-norm
    }
    curs[t] = excl;
    __syncthreads();
    for (int i = ebeg + t; i < eend; i += 256) {
      unsigned u = eb[i];
      int l = atomicAdd(&curs[u >> 24], 1);
      sb[ebeg + l] = (int)(u & 0xFFFFFFu);
    }
    __syncthreads();
  }
}

// ---- P = feat * ns, both graphs -> P[2n][64], 8 elems/thread ----
__global__ void k_scale_all(const void* __restrict__ f1, const void* __restrict__ f2,
                            const float* __restrict__ norms, bf16* __restrict__ P,
                            int n, const int* __restrict__ mode) {
  int m = *mode;
  long i8 = ((long)blockIdx.x * 256 + threadIdx.x) * 8;
  long nd = (long)n * DIM;
  if (i8 >= 2 * nd) return;
  int g = i8 >= nd;
  long li = g ? i8 - nd : i8;
  float ns = norms[2 * n + g * n + (int)(li >> 6)];
  const void* f = g ? f2 : f1;
  float x[8];
  if (m) {
    const float4* fp = (const float4*)((const char*)f + li * 4);
    float4 a = fp[0], b = fp[1];
    x[0] = a.x; x[1] = a.y; x[2] = a.z; x[3] = a.w;
    x[4] = b.x; x[5] = b.y; x[6] = b.z; x[7] = b.w;
  } else {
    const ushort4* hp = (const ushort4*)((const char*)f + li * 2);
    ushort4 a = hp[0], b = hp[1];
    x[0] = bfbits2f(a.x); x[1] = bfbits2f(a.y);
    x[2] = bfbits2f(a.z); x[3] = bfbits2f(a.w);
    x[4] = bfbits2f(b.x); x[5] = bfbits2f(b.y);
    x[6] = bfbits2f(b.z); x[7] = bfbits2f(b.w);
  }
  uint4 o;
  o.x = f2bf_bits(x[0] * ns) | ((unsigned)f2bf_bits(x[1] * ns) << 16);
  o.y = f2bf_bits(x[2] * ns) | ((unsigned)f2bf_bits(x[3] * ns) << 16);
  o.z = f2bf_bits(x[4] * ns) | ((unsigned)f2bf_bits(x[5] * ns) << 16);
  o.w = f2bf_bits(x[6] * ns) | ((unsigned)f2bf_bits(x[7] * ns) << 16);
  *(uint4*)((char*)P + i8 * 2) = o;
}

// ---- P = feat * ns, one graph (fallback) ----
__global__ void k_scale_one(const void* __restrict__ f, const float* __restrict__ ns,
                            bf16* __restrict__ P, int nd, const int* __restrict__ mode) {
  int m = *mode;
  int i = blockIdx.x * 256 + threadIdx.x;
  if (i < nd) P[i] = __float2bfloat16(ldf(f, i, m) * ns[i >> 6]);
}

// ---- fused CSR gather + 64x64 matmul (+ optional column stats) ----
// Measured-floor implementation. The gather is capped by per-CU L1
// miss-concurrency (~32 lines in flight @ ~700cy round-trip = ~26G lines/s
// chip-wide — matches 6.4M lines / 244us). Issue-side restructures (R1-R5)
// cannot move this. DO NOT RESTRUCTURE.
__global__ void __launch_bounds__(256) k_gmm(
    const bf16* __restrict__ X, const int* __restrict__ rp, const int* __restrict__ sb,
    const void* __restrict__ Wg0, const void* __restrict__ bg0,
    const void* __restrict__ Wg1, const void* __restrict__ bg1,
    const float* __restrict__ pre0, const float* __restrict__ pre1,
    const float* __restrict__ post0, const float* __restrict__ post1,
    bf16* __restrict__ Y, int n, int relu, const int* __restrict__ mode,
    int dual, int gsel, float* __restrict__ stats) {
  int m = *mode;
  int t = threadIdx.x, lane = t & 63, wid = t >> 6;
  int g = dual ? (blockIdx.x & 1) : gsel;
  int ord = dual ? (blockIdx.x >> 1) : blockIdx.x;
  int nblk = dual ? (gridDim.x >> 1) : gridDim.x;
  int rowbase = dual ? g * n : 0;

  const void* W = g ? Wg1 : Wg0;
  const void* bb = g ? bg1 : bg0;
  const float* pre = g ? pre1 : pre0;
  const float* post = g ? post1 : post0;

  unsigned wp[32];
#pragma unroll
  for (int i = 0; i < 32; ++i) {
    unsigned lb = f2bf_bits(ldf(W, (2 * i) * 64 + lane, m));
    unsigned hb = f2bf_bits(ldf(W, (2 * i + 1) * 64 + lane, m));
    wp[i] = lb | (hb << 16);
  }
  float bias = ldf(bb, lane, m);
  float ps = 0.f, pq = 0.f;

  int stride = nblk * 4;
  for (int node = ord * 4 + wid; node < n; node += stride) {
    int b0 = rp[g * n + node], e0 = rp[g * n + node + 1];
    float a0 = 0.f, a1 = 0.f, a2 = 0.f, a3 = 0.f;
    for (int base = b0; base < e0; base += 64) {
      int cnt = e0 - base;
      if (cnt > 64) cnt = 64;
      int eidx = (lane < cnt) ? sb[base + lane] : 0;
      int j = 0;
      for (; j + 8 <= cnt; j += 8) {
        int s0 = __builtin_amdgcn_readlane(eidx, j);
        int s1 = __builtin_amdgcn_readlane(eidx, j + 1);
        int s2 = __builtin_amdgcn_readlane(eidx, j + 2);
        int s3 = __builtin_amdgcn_readlane(eidx, j + 3);
        int s4 = __builtin_amdgcn_readlane(eidx, j + 4);
        int s5 = __builtin_amdgcn_readlane(eidx, j + 5);
        int s6 = __builtin_amdgcn_readlane(eidx, j + 6);
        int s7 = __builtin_amdgcn_readlane(eidx, j + 7);
        float v0 = __bfloat162float(X[(long)(rowbase + s0) * DIM + lane]);
        float v1 = __bfloat162float(X[(long)(rowbase + s1) * DIM + lane]);
        float v2 = __bfloat162float(X[(long)(rowbase + s2) * DIM + lane]);
        float v3 = __bfloat162float(X[(long)(rowbase + s3) * DIM + lane]);
        float v4 = __bfloat162float(X[(long)(rowbase + s4) * DIM + lane]);
        float v5 = __bfloat162float(X[(long)(rowbase + s5) * DIM + lane]);
        float v6 = __bfloat162float(X[(long)(rowbase + s6) * DIM + lane]);
        float v7 = __bfloat162float(X[(long)(rowbase + s7) * DIM + lane]);
        a0 += v0; a1 += v1; a2 += v2; a3 += v3;
        a0 += v4; a1 += v5; a2 += v6; a3 += v7;
      }
      for (; j + 4 <= cnt; j += 4) {
        int s0 = __builtin_amdgcn_readlane(eidx, j);
        int s1 = __builtin_amdgcn_readlane(eidx, j + 1);
        int s2 = __builtin_amdgcn_readlane(eidx, j + 2);
        int s3 = __builtin_amdgcn_readlane(eidx, j + 3);
        a0 += __bfloat162float(X[(long)(rowbase + s0) * DIM + lane]);
        a1 += __bfloat162float(X[(long)(rowbase + s1) * DIM + lane]);
        a2 += __bfloat162float(X[(long)(rowbase + s2) * DIM + lane]);
        a3 += __bfloat162float(X[(long)(rowbase + s3) * DIM + lane]);
      }
      for (; j < cnt; ++j) {
        int s0 = __builtin_amdgcn_readlane(eidx, j);
        a0 += __bfloat162float(X[(long)(rowbase + s0) * DIM + lane]);
      }
    }
    float acc = (a0 + a1) + (a2 + a3);
    acc *= pre[node];
    float r = 0.f;
#pragma unroll
    for (int i = 0; i < 32; ++i) {
      r = fmaf(lane_bcast(acc, 2 * i), __uint_as_float(wp[i] << 16), r);
      r = fmaf(lane_bcast(acc, 2 * i + 1), __uint_as_float(wp[i] & 0xFFFF0000u), r);
    }
    r += bias;
    if (relu) r = fmaxf(r, 0.f);
    if (post) r *= post[node];
    Y[(long)(rowbase + node) * DIM + lane] = __float2bfloat16(r);
    ps += r;
    pq += r * r;
  }

  if (stats) {
    __shared__ float ssum[4][64], ssq[4][64];
    ssum[wid][lane] = ps;
    ssq[wid][lane] = pq;
    __syncthreads();
    if (t < 64) {
      float a = ssum[0][t] + ssum[1][t] + ssum[2][t] + ssum[3][t];
      float b2 = ssq[0][t] + ssq[1][t] + ssq[2][t] + ssq[3][t];
      atomicAdd(&stats[g * 128 + t], a);
      atomicAdd(&stats[g * 128 + 64 + t], b2);
    }
  }
}

// ---- fused dual standardize + head matmul: z1,z2 -> out; y = Dz@Wm1+bm1 ----
__global__ void __launch_bounds__(256) k_zmm(const bf16* __restrict__ H,
                                             const float* __restrict__ stats,
                                             void* __restrict__ zout,
                                             const void* __restrict__ Wm,
                                             const void* __restrict__ bm,
                                             bf16* __restrict__ Y, int n,
                                             const int* __restrict__ mode,
                                             float* __restrict__ ystats) {
  int m = *mode;
  int t = threadIdx.x, lane = t & 63, wid = t >> 6;
  float w[64];
#pragma unroll
  for (int k = 0; k < 64; ++k) w[k] = ldf(Wm, k * 64 + lane, m);
  float bias = ldf(bm, lane, m);
  float fn = (float)n;
  float mu1 = stats[lane] / fn;
  float var1 = fmaxf((stats[64 + lane] - mu1 * mu1 * fn) / (fn - 1.0f), 1e-12f);
  float mu2 = stats[128 + lane] / fn;
  float var2 = fmaxf((stats[192 + lane] - mu2 * mu2 * fn) / (fn - 1.0f), 1e-12f);
  float rs1 = rsqrtf(var1), rs2 = rsqrtf(var2);
  long nd = (long)n * DIM;
  float ps = 0.f, pq = 0.f;
  int stride = gridDim.x * 4;
  for (int row = blockIdx.x * 4 + wid; row < n; row += stride) {
    long idx = (long)row * DIM + lane;
    float z1 = (__bfloat162float(H[idx]) - mu1) * rs1;
    float z2 = (__bfloat162float(H[nd + idx]) - mu2) * rs2;
    stf(zout, idx, z1, m);
    stf(zout, nd + idx, z2, m);
    float dz = 0.5f * (z1 + z2);
    float acc = 0.f;
#pragma unroll
    for (int k = 0; k < 64; ++k) acc = fmaf(lane_bcast(dz, k), w[k], acc);
    acc += bias;
    Y[idx] = __float2bfloat16(acc);
    ps += acc;
    pq += acc * acc;
  }
  __shared__ float ssum[4][64], ssq[4][64];
  ssum[wid][lane] = ps;
  ssq[wid][lane] = pq;
  __syncthreads();
  if (t < 64) {
    float a = ssum[0][t] + ssum[1][t] + ssum[2][t] + ssum[3][t];
    float b2 = ssq[0][t] + ssq[1][t] + ssq[2][t] + ssq[3][t];
    atomicAdd(&ystats[t], a);
    atomicAdd(&ystats[64 + t], b2);
  }
}

// ---- head 64x64 matmul + fused column stats (fallback path) ----
__global__ void __launch_bounds__(256) k_mm64s(const bf16* __restrict__ X,
                                               const void* __restrict__ W,
                                               const void* __restrict__ b,
                                               bf16* __restrict__ Y, int n,
                                               const int* __restrict__ mode,
                                               float* __restrict__ stats) {
  int m = *mode;
  int t = threadIdx.x, lane = t & 63, wid = t >> 6;
  float w[64];
#pragma unroll
  for (int k = 0; k < 64; ++k) w[k] = ldf(W, k * 64 + lane, m);
  float bias = ldf(b, lane, m);
  float ps = 0.f, pq = 0.f;
  int stride = gridDim.x * 4;
  for (int row = blockIdx.x * 4 + wid; row < n; row += stride) {
    float a = __bfloat162float(X[(long)row * 64 + lane]);
    float acc = 0.f;
#pragma unroll
    for (int k = 0; k < 64; ++k) acc = fmaf(lane_bcast(a, k), w[k], acc);
    acc += bias;
    Y[(long)row * 64 + lane] = __float2bfloat16(acc);
    ps += acc;
    pq += acc * acc;
  }
  __shared__ float ssum[4][64], ssq[4][64];
  ssum[wid][lane] = ps;
  ssq[wid][lane] = pq;
  __syncthreads();
  if (t < 64) {
    float a = ssum[0][t] + ssum[1][t] + ssum[2][t] + ssum[3][t];
    float b2 = ssq[0][t] + ssq[1][t] + ssq[2][t] + ssq[3][t];
    atomicAdd(&stats[t], a);
    atomicAdd(&stats[64 + t], b2);
  }
}

// ---- sequential standardize (fallback) ----
__global__ void k_z_seq(const bf16* __restrict__ h, const float* __restrict__ stats,
                        void* __restrict__ zout, long zoff, bf16* __restrict__ zacc,
                        int n, int init, const int* __restrict__ mode) {
  int m = *mode;
  int i = blockIdx.x * 256 + threadIdx.x;
  if (i >= n * DIM) return;
  int c = i & 63;
  float fn = (float)n;
  float mu = stats[c] / fn;
  float var = fmaxf((stats[64 + c] - mu * mu * fn) / (fn - 1.0f), 1e-12f);
  float z = (__bfloat162float(h[i]) - mu) * rsqrtf(var);
  stf(zout, zoff + i, z, m);
  float prev = init ? 0.f : __bfloat162float(zacc[i]);
  zacc[i] = __float2bfloat16(prev + 0.5f * z);
}

// ---- BN + relu + 64x40 matmul -> logits ----
__global__ void __launch_bounds__(256) k_head(const bf16* __restrict__ Yv,
                                              const float* __restrict__ s,
                                              const float* __restrict__ sq,
                                              const void* __restrict__ gamma,
                                              const void* __restrict__ beta,
                                              const void* __restrict__ W2,
                                              const void* __restrict__ b2,
                                              void* __restrict__ out, long ooff, int n,
                                              const int* __restrict__ mode) {
  int m = *mode;
  int t = threadIdx.x, lane = t & 63, wid = t >> 6;
  float w[64];
#pragma unroll
  for (int k = 0; k < 64; ++k)
    w[k] = (lane < NCLS_OUT) ? ldf(W2, k * NCLS_OUT + lane, m) : 0.f;
  float bias = (lane < NCLS_OUT) ? ldf(b2, lane, m) : 0.f;
  float fn = (float)n;
  float mu = s[lane] / fn;
  float var = sq[lane] / fn - mu * mu;
  float rstd = rsqrtf(fmaxf(var, 0.f) + 1e-5f);
  float g = ldf(gamma, lane, m);
  float be = ldf(beta, lane, m);
  int stride = gridDim.x * 4;
  for (int row = blockIdx.x * 4 + wid; row < n; row += stride) {
    float yv = __bfloat162float(Yv[(long)row * 64 + lane]);
    float yn = fmaxf((yv - mu) * rstd * g + be, 0.f);
    float acc = bias;
#pragma unroll
    for (int k = 0; k < 64; ++k) acc = fmaf(lane_bcast(yn, k), w[k], acc);
    if (lane < NCLS_OUT) stf(out, ooff + (long)row * NCLS_OUT + lane, acc, m);
  }
}

extern "C" void kernel_launch(void* const* d_in, const int* in_sizes, int n_in,
                              void* d_out, int out_size, void* d_ws, size_t ws_size,
                              hipStream_t stream) {
  const void* feat1 = d_in[0];
  const int* src1 = (const int*)d_in[1];
  const int* dst1 = (const int*)d_in[2];
  const void* feat2 = d_in[3];
  const int* src2 = (const int*)d_in[4];
  const int* dst2 = (const int*)d_in[5];
  const void* W1a = d_in[6];
  const void* b1a = d_in[7];
  const void* W1b = d_in[8];
  const void* b1b = d_in[9];
  const void* W2a = d_in[10];
  const void* b2a = d_in[11];
  const void* W2b = d_in[12];
  const void* b2b = d_in[13];
  const void* Wm1 = d_in[14];
  const void* bm1 = d_in[15];
  const void* gamma = d_in[16];
  const void* beta = d_in[17];
  const void* Wm2 = d_in[18];
  const void* bm2 = d_in[19];

  const int n = in_sizes[0] / DIM;
  const int e1 = in_sizes[1];
  const int e2 = in_sizes[4];
  const int etot = e1 + e2;
  const long nd = (long)n * DIM;
  const int NB = (2 * n + BROWS - 1) >> BSH;

  char* w = (char*)d_ws;
  size_t off = 0;
  auto alloc = [&](size_t bytes) -> void* {
    void* p = w + off;
    off += (bytes + 255) & ~(size_t)255;
    return p;
  };
  int* mode = (int*)alloc(256);
  int* deg = (int*)alloc((size_t)4 * n * 4);
  float* stats = (float*)alloc(512 * 4);
  float* norms = (float*)alloc((size_t)4 * n * 4);
  int* rp = (int*)alloc((size_t)(2 * n + 8) * 4);
  int* bh = (int*)alloc((size_t)(NB + 1) * 4);
  int* bbase = (int*)alloc((size_t)(NB + 1) * 4);
  int* gcur = (int*)alloc((size_t)(NB + 1) * 4);
  int* sb = (int*)alloc((size_t)etot * 4);
  size_t base_off = off;
  bool dual = (ws_size >= base_off + (size_t)5 * nd * 2 + 4096);

  bf16 *P, *Q, *Dz;
  size_t qbytes;
  if (dual) {
    P = (bf16*)alloc((size_t)2 * nd * 2);
    Q = (bf16*)alloc((size_t)2 * nd * 2);
    Dz = (bf16*)alloc((size_t)nd * 2);
    qbytes = (size_t)2 * nd * 2;
  } else {
    P = (bf16*)alloc((size_t)nd * 2);
    Q = (bf16*)alloc((size_t)nd * 2);
    Dz = (bf16*)alloc((size_t)nd * 2);
    qbytes = (size_t)nd * 2;
  }
  // eb (bucket-grouped packed edges) is dead before gmm1 first writes Q, so
  // alias it onto Q when it fits; else take fresh workspace.
  unsigned* eb = ((size_t)etot * 4 <= qbytes) ? (unsigned*)Q
                                              : (unsigned*)alloc((size_t)etot * 4);

  const float* nd1 = norms;
  const float* nd2 = norms + n;
  const float* ns1 = norms + 2 * n;
  const float* ns2 = norms + 3 * n;

  int gND = (int)((nd + 255) / 256);
  int g2ND8 = (int)((2 * nd / 8 + 255) / 256);
  int gBIN = (etot + BIN_CHUNK - 1) / BIN_CHUNK;
  const int gGMM = 4096;

  hipMemsetAsync(deg + 2 * n, 0, (size_t)2 * n * 4, stream);
  hipMemsetAsync(stats, 0, 512 * 4, stream);
  hipMemsetAsync(bh, 0, (size_t)NB * 4, stream);

  k_detect<<<1, 1024, 0, stream>>>((const unsigned int*)feat1, 8192, mode);

  // dst-only bucket histogram, then bucket sort (out-degree folded into k_bin)
  k_bh<<<256, 256, (size_t)NB * 4, stream>>>(dst1, dst2, bh, n, e1, etot, NB);
  k_bscan<<<1, 256, 0, stream>>>(bh, bbase, gcur, rp, NB, etot, 2 * n);
  k_bin<<<gBIN, 256, (size_t)2 * NB * 4, stream>>>(src1, dst1, src2, dst2, gcur, eb,
                                                   deg, n, e1, etot, NB);
  k_fine<<<NB, 256, 0, stream>>>(eb, bbase, rp, deg, norms, sb, 2 * n, NB);

  if (dual) {
    k_scale_all<<<g2ND8, 256, 0, stream>>>(feat1, feat2, norms, P, n, mode);
    k_gmm<<<gGMM, 256, 0, stream>>>(P, rp, sb, W1a, b1a, W2a, b2a, nd1, nd2, ns1, ns2,
                                    Q, n, 1, mode, 1, 0, (float*)nullptr);
    k_gmm<<<gGMM, 256, 0, stream>>>(Q, rp, sb, W1b, b1b, W2b, b2b, nd1, nd2,
                                    (const float*)nullptr, (const float*)nullptr,
                                    P, n, 0, mode, 1, 0, stats);
    // fused standardize + head matmul (Dz in registers)
    k_zmm<<<512, 256, 0, stream>>>(P, stats, d_out, Wm1, bm1, Q, n, mode, stats + 256);
  } else {
    // graph 1
    k_scale_one<<<gND, 256, 0, stream>>>(feat1, ns1, P, (int)nd, mode);
    k_gmm<<<gGMM, 256, 0, stream>>>(P, rp, sb, W1a, b1a, W1a, b1a, nd1, nd1, ns1, ns1,
                                    Q, n, 1, mode, 0, 0, (float*)nullptr);
    k_gmm<<<gGMM, 256, 0, stream>>>(Q, rp, sb, W1b, b1b, W1b, b1b, nd1, nd1,
                                    (const float*)nullptr, (const float*)nullptr,
                                    P, n, 0, mode, 0, 0, stats);
    k_z_seq<<<gND, 256, 0, stream>>>(P, stats, d_out, 0L, Dz, n, 1, mode);
    // graph 2
    k_scale_one<<<gND, 256, 0, stream>>>(feat2, ns2, P, (int)nd, mode);
    k_gmm<<<gGMM, 256, 0, stream>>>(P, rp, sb, W2a, b2a, W2a, b2a, nd2, nd2, ns2, ns2,
                                    Q, n, 1, mode, 0, 1, (float*)nullptr);
    k_gmm<<<gGMM, 256, 0, stream>>>(Q, rp, sb, W2b, b2b, W2b, b2b, nd2, nd2,
                                    (const float*)nullptr, (const float*)nullptr,
                                    P, n, 0, mode, 0, 1, stats + 128);
    k_z_seq<<<gND, 256, 0, stream>>>(P, stats + 128, d_out, nd, Dz, n, 0, mode);
    k_mm64s<<<512, 256, 0, stream>>>(Dz, Wm1, bm1, Q, n, mode, stats + 256);
  }

  // BN ; relu ; @Wm2+bm2
  k_head<<<512, 256, 0, stream>>>(Q, stats + 256, stats + 320, gamma, beta, Wm2, bm2,
                                  d_out, 2 * nd, n, mode);
}

// Round 11
// 940.182 us; speedup vs baseline: 1.0188x; 1.0188x over previous
//
#include <hip/hip_runtime.h>
#include <hip/hip_bf16.h>

#define DIM 64
#define NCLS_OUT 40
#define BSH 8          // rows per bucket = 256
#define BROWS 256
#define BIN_CHUNK 12288

typedef __hip_bfloat16 bf16;

__device__ __forceinline__ float lane_bcast(float v, int l) {
  return __int_as_float(__builtin_amdgcn_readlane(__float_as_int(v), l));
}
__device__ __forceinline__ unsigned short f2bf_bits(float f) {
  bf16 h = __float2bfloat16(f);
  return *reinterpret_cast<unsigned short*>(&h);
}
__device__ __forceinline__ float bfbits2f(unsigned short u) {
  return __uint_as_float((unsigned)u << 16);
}

// mode: 1 = float inputs/outputs stored as f32, 0 = stored as bf16
__device__ __forceinline__ float ldf(const void* p, long i, int m) {
  return m ? ((const float*)p)[i] : __bfloat162float(((const bf16*)p)[i]);
}
__device__ __forceinline__ void stf(void* p, long i, float v, int m) {
  if (m) ((float*)p)[i] = v;
  else ((bf16*)p)[i] = __float2bfloat16(v);
}

// ---- dtype detector ----
__global__ void k_detect(const unsigned int* __restrict__ wds, int nw, int* __restrict__ mode) {
  __shared__ int cnt_s;
  if (threadIdx.x == 0) cnt_s = 0;
  __syncthreads();
  int c = 0;
  for (int i = threadIdx.x; i < nw; i += 1024) {
    unsigned h = wds[i] & 0xFFFFu;
    unsigned e = (h >> 7) & 0xFFu;
    if (e == 0xFFu || (e != 0u && e < 0x60u)) c++;
  }
  atomicAdd(&cnt_s, c);
  __syncthreads();
  if (threadIdx.x == 0) *mode = (cnt_s > nw / 16) ? 1 : 0;
}

// ---- fused: out-degree atomics + dst bucket histogram (one edge-list pass) ----
// deg layout: [d1in | d2in | d1out | d2out]; this fills the out half.
// (R9 lesson: folding these atomics into k_bin's scatter loop regresses —
// here they overlap a pure stream; there they serialize with eb stores.)
__global__ void k_deg_hist(const int* __restrict__ src1, const int* __restrict__ dst1,
                           const int* __restrict__ src2, const int* __restrict__ dst2,
                           int* __restrict__ deg, int* __restrict__ bh,
                           int n, int e1, int etot, int NB) {
  extern __shared__ int cnt[];
  for (int b = threadIdx.x; b < NB; b += blockDim.x) cnt[b] = 0;
  __syncthreads();
  int stride = gridDim.x * blockDim.x;
  for (int i = blockIdx.x * blockDim.x + threadIdx.x; i < etot; i += stride) {
    int s, row;
    if (i < e1) { s = src1[i]; row = dst1[i]; }
    else { s = n + src2[i - e1]; row = n + dst2[i - e1]; }
    atomicAdd(&deg[2 * n + s], 1);
    atomicAdd(&cnt[row >> BSH], 1);
  }
  __syncthreads();
  for (int b = threadIdx.x; b < NB; b += blockDim.x)
    if (cnt[b]) atomicAdd(&bh[b], cnt[b]);
}

// ---- scan bucket counts -> bucket bases (single block; NB is small) ----
__global__ void k_bscan(const int* __restrict__ bh, int* __restrict__ bbase,
                        int* __restrict__ gcur, int* __restrict__ rp,
                        int NB, int etot, int n2) {
  __shared__ int sm[256];
  __shared__ int carry_s;
  int t = threadIdx.x;
  if (t == 0) carry_s = 0;
  __syncthreads();
  for (int base = 0; base < NB; base += 256) {
    int i = base + t;
    int v = (i < NB) ? bh[i] : 0;
    sm[t] = v;
    __syncthreads();
    for (int o = 1; o < 256; o <<= 1) {
      int a = (t >= o) ? sm[t - o] : 0;
      __syncthreads();
      sm[t] += a;
      __syncthreads();
    }
    int c = carry_s;
    int excl = c + sm[t] - v;
    int tot = sm[255];
    __syncthreads();
    if (i < NB) { bbase[i] = excl; gcur[i] = excl; }
    if (t == 0) carry_s = c + tot;
    __syncthreads();
  }
  if (t == 0) { bbase[NB] = etot; rp[n2] = etot; }
}

// ---- binning scatter: edges -> bucket-grouped eb[] ----
__global__ void __launch_bounds__(256) k_bin(
    const int* __restrict__ src1, const int* __restrict__ dst1,
    const int* __restrict__ src2, const int* __restrict__ dst2,
    int* __restrict__ gcur, unsigned* __restrict__ eb,
    int n, int e1, int etot, int NB) {
  extern __shared__ int lds[];
  int* cnt = lds;       // NB
  int* base = lds + NB; // NB
  int t = threadIdx.x;
  int c0 = blockIdx.x * BIN_CHUNK;
  int cend = c0 + BIN_CHUNK;
  if (cend > etot) cend = etot;
  for (int b = t; b < NB; b += 256) cnt[b] = 0;
  __syncthreads();
  for (int i = c0 + t; i < cend; i += 256) {
    int row = (i < e1) ? dst1[i] : (n + dst2[i - e1]);
    atomicAdd(&cnt[row >> BSH], 1);
  }
  __syncthreads();
  for (int b = t; b < NB; b += 256) {
    int c = cnt[b];
    base[b] = c ? atomicAdd(&gcur[b], c) : 0;
    cnt[b] = 0;  // reuse as local cursor
  }
  __syncthreads();
  for (int i = c0 + t; i < cend; i += 256) {
    int s, row;
    if (i < e1) { s = src1[i]; row = dst1[i]; }
    else { s = src2[i - e1]; row = n + dst2[i - e1]; }
    int b = row >> BSH;
    int l = atomicAdd(&cnt[b], 1);
    eb[base[b] + l] = ((unsigned)(row & (BROWS - 1)) << 24) | (unsigned)s;
  }
}

// ---- fine fill: one block per bucket ----
// LDS histogram -> in-degree norms + rp (LDS scan) + sb scatter in the
// bucket's L2-resident slice. Also computes OUT norms for its row range
// (deg out-half is complete by now; out-half starts at deg[n2]).
__global__ void __launch_bounds__(256) k_fine(
    const unsigned* __restrict__ eb, const int* __restrict__ bbase,
    int* __restrict__ rp, const int* __restrict__ deg, float* __restrict__ nrm,
    int* __restrict__ sb, int n2, int NB) {
  __shared__ int hist[256];
  __shared__ int sm[256];
  __shared__ int curs[256];
  int t = threadIdx.x;
  for (int b = blockIdx.x; b < NB; b += gridDim.x) {
    int ebeg = bbase[b], eend = bbase[b + 1];
    hist[t] = 0;
    __syncthreads();
    for (int i = ebeg + t; i < eend; i += 256)
      atomicAdd(&hist[eb[i] >> 24], 1);
    __syncthreads();
    int v = hist[t];
    sm[t] = v;
    __syncthreads();
    for (int o = 1; o < 256; o <<= 1) {
      int a = (t >= o) ? sm[t - o] : 0;
      __syncthreads();
      sm[t] += a;
      __syncthreads();
    }
    int excl = sm[t] - v;
    int row = (b << BSH) + t;
    if (row < n2) {
      rp[row] = ebeg + excl;
      nrm[row] = rsqrtf((float)(v < 1 ? 1 : v));                 // in-norm
      int dov = deg[n2 + row];                                   // deg[2n+row]
      nrm[n2 + row] = rsqrtf((float)(dov < 1 ? 1 : dov));        // out-norm
    }
    curs[t] = excl;
    __syncthreads();
    for (int i = ebeg + t; i < eend; i += 256) {
      unsigned u = eb[i];
      int l = atomicAdd(&curs[u >> 24], 1);
      sb[ebeg + l] = (int)(u & 0xFFFFFFu);
    }
    __syncthreads();
  }
}

// ---- P = feat * ns, both graphs -> P[2n][64], 8 elems/thread ----
__global__ void k_scale_all(const void* __restrict__ f1, const void* __restrict__ f2,
                            const float* __restrict__ norms, bf16* __restrict__ P,
                            int n, const int* __restrict__ mode) {
  int m = *mode;
  long i8 = ((long)blockIdx.x * 256 + threadIdx.x) * 8;
  long nd = (long)n * DIM;
  if (i8 >= 2 * nd) return;
  int g = i8 >= nd;
  long li = g ? i8 - nd : i8;
  float ns = norms[2 * n + g * n + (int)(li >> 6)];
  const void* f = g ? f2 : f1;
  float x[8];
  if (m) {
    const float4* fp = (const float4*)((const char*)f + li * 4);
    float4 a = fp[0], b = fp[1];
    x[0] = a.x; x[1] = a.y; x[2] = a.z; x[3] = a.w;
    x[4] = b.x; x[5] = b.y; x[6] = b.z; x[7] = b.w;
  } else {
    const ushort4* hp = (const ushort4*)((const char*)f + li * 2);
    ushort4 a = hp[0], b = hp[1];
    x[0] = bfbits2f(a.x); x[1] = bfbits2f(a.y);
    x[2] = bfbits2f(a.z); x[3] = bfbits2f(a.w);
    x[4] = bfbits2f(b.x); x[5] = bfbits2f(b.y);
    x[6] = bfbits2f(b.z); x[7] = bfbits2f(b.w);
  }
  uint4 o;
  o.x = f2bf_bits(x[0] * ns) | ((unsigned)f2bf_bits(x[1] * ns) << 16);
  o.y = f2bf_bits(x[2] * ns) | ((unsigned)f2bf_bits(x[3] * ns) << 16);
  o.z = f2bf_bits(x[4] * ns) | ((unsigned)f2bf_bits(x[5] * ns) << 16);
  o.w = f2bf_bits(x[6] * ns) | ((unsigned)f2bf_bits(x[7] * ns) << 16);
  *(uint4*)((char*)P + i8 * 2) = o;
}

// ---- P = feat * ns, one graph (fallback) ----
__global__ void k_scale_one(const void* __restrict__ f, const float* __restrict__ ns,
                            bf16* __restrict__ P, int nd, const int* __restrict__ mode) {
  int m = *mode;
  int i = blockIdx.x * 256 + threadIdx.x;
  if (i < nd) P[i] = __float2bfloat16(ldf(f, i, m) * ns[i >> 6]);
}

// ---- fused CSR gather + 64x64 matmul (+ optional column stats) ----
// Measured-floor implementation. The gather is capped by per-CU L1
// miss-concurrency (~32 lines in flight @ ~700cy round-trip = ~26G lines/s
// chip-wide — matches 6.4M lines / 244us). Issue-side restructures (R1-R5)
// cannot move this. DO NOT RESTRUCTURE.
__global__ void __launch_bounds__(256) k_gmm(
    const bf16* __restrict__ X, const int* __restrict__ rp, const int* __restrict__ sb,
    const void* __restrict__ Wg0, const void* __restrict__ bg0,
    const void* __restrict__ Wg1, const void* __restrict__ bg1,
    const float* __restrict__ pre0, const float* __restrict__ pre1,
    const float* __restrict__ post0, const float* __restrict__ post1,
    bf16* __restrict__ Y, int n, int relu, const int* __restrict__ mode,
    int dual, int gsel, float* __restrict__ stats) {
  int m = *mode;
  int t = threadIdx.x, lane = t & 63, wid = t >> 6;
  int g = dual ? (blockIdx.x & 1) : gsel;
  int ord = dual ? (blockIdx.x >> 1) : blockIdx.x;
  int nblk = dual ? (gridDim.x >> 1) : gridDim.x;
  int rowbase = dual ? g * n : 0;

  const void* W = g ? Wg1 : Wg0;
  const void* bb = g ? bg1 : bg0;
  const float* pre = g ? pre1 : pre0;
  const float* post = g ? post1 : post0;

  unsigned wp[32];
#pragma unroll
  for (int i = 0; i < 32; ++i) {
    unsigned lb = f2bf_bits(ldf(W, (2 * i) * 64 + lane, m));
    unsigned hb = f2bf_bits(ldf(W, (2 * i + 1) * 64 + lane, m));
    wp[i] = lb | (hb << 16);
  }
  float bias = ldf(bb, lane, m);
  float ps = 0.f, pq = 0.f;

  int stride = nblk * 4;
  for (int node = ord * 4 + wid; node < n; node += stride) {
    int b0 = rp[g * n + node], e0 = rp[g * n + node + 1];
    float a0 = 0.f, a1 = 0.f, a2 = 0.f, a3 = 0.f;
    for (int base = b0; base < e0; base += 64) {
      int cnt = e0 - base;
      if (cnt > 64) cnt = 64;
      int eidx = (lane < cnt) ? sb[base + lane] : 0;
      int j = 0;
      for (; j + 8 <= cnt; j += 8) {
        int s0 = __builtin_amdgcn_readlane(eidx, j);
        int s1 = __builtin_amdgcn_readlane(eidx, j + 1);
        int s2 = __builtin_amdgcn_readlane(eidx, j + 2);
        int s3 = __builtin_amdgcn_readlane(eidx, j + 3);
        int s4 = __builtin_amdgcn_readlane(eidx, j + 4);
        int s5 = __builtin_amdgcn_readlane(eidx, j + 5);
        int s6 = __builtin_amdgcn_readlane(eidx, j + 6);
        int s7 = __builtin_amdgcn_readlane(eidx, j + 7);
        float v0 = __bfloat162float(X[(long)(rowbase + s0) * DIM + lane]);
        float v1 = __bfloat162float(X[(long)(rowbase + s1) * DIM + lane]);
        float v2 = __bfloat162float(X[(long)(rowbase + s2) * DIM + lane]);
        float v3 = __bfloat162float(X[(long)(rowbase + s3) * DIM + lane]);
        float v4 = __bfloat162float(X[(long)(rowbase + s4) * DIM + lane]);
        float v5 = __bfloat162float(X[(long)(rowbase + s5) * DIM + lane]);
        float v6 = __bfloat162float(X[(long)(rowbase + s6) * DIM + lane]);
        float v7 = __bfloat162float(X[(long)(rowbase + s7) * DIM + lane]);
        a0 += v0; a1 += v1; a2 += v2; a3 += v3;
        a0 += v4; a1 += v5; a2 += v6; a3 += v7;
      }
      for (; j + 4 <= cnt; j += 4) {
        int s0 = __builtin_amdgcn_readlane(eidx, j);
        int s1 = __builtin_amdgcn_readlane(eidx, j + 1);
        int s2 = __builtin_amdgcn_readlane(eidx, j + 2);
        int s3 = __builtin_amdgcn_readlane(eidx, j + 3);
        a0 += __bfloat162float(X[(long)(rowbase + s0) * DIM + lane]);
        a1 += __bfloat162float(X[(long)(rowbase + s1) * DIM + lane]);
        a2 += __bfloat162float(X[(long)(rowbase + s2) * DIM + lane]);
        a3 += __bfloat162float(X[(long)(rowbase + s3) * DIM + lane]);
      }
      for (; j < cnt; ++j) {
        int s0 = __builtin_amdgcn_readlane(eidx, j);
        a0 += __bfloat162float(X[(long)(rowbase + s0) * DIM + lane]);
      }
    }
    float acc = (a0 + a1) + (a2 + a3);
    acc *= pre[node];
    float r = 0.f;
#pragma unroll
    for (int i = 0; i < 32; ++i) {
      r = fmaf(lane_bcast(acc, 2 * i), __uint_as_float(wp[i] << 16), r);
      r = fmaf(lane_bcast(acc, 2 * i + 1), __uint_as_float(wp[i] & 0xFFFF0000u), r);
    }
    r += bias;
    if (relu) r = fmaxf(r, 0.f);
    if (post) r *= post[node];
    Y[(long)(rowbase + node) * DIM + lane] = __float2bfloat16(r);
    ps += r;
    pq += r * r;
  }

  if (stats) {
    __shared__ float ssum[4][64], ssq[4][64];
    ssum[wid][lane] = ps;
    ssq[wid][lane] = pq;
    __syncthreads();
    if (t < 64) {
      float a = ssum[0][t] + ssum[1][t] + ssum[2][t] + ssum[3][t];
      float b2 = ssq[0][t] + ssq[1][t] + ssq[2][t] + ssq[3][t];
      atomicAdd(&stats[g * 128 + t], a);
      atomicAdd(&stats[g * 128 + 64 + t], b2);
    }
  }
}

// ---- fused dual standardize + head matmul: z1,z2 -> out; y = Dz@Wm1+bm1 ----
__global__ void __launch_bounds__(256) k_zmm(const bf16* __restrict__ H,
                                             const float* __restrict__ stats,
                                             void* __restrict__ zout,
                                             const void* __restrict__ Wm,
                                             const void* __restrict__ bm,
                                             bf16* __restrict__ Y, int n,
                                             const int* __restrict__ mode,
                                             float* __restrict__ ystats) {
  int m = *mode;
  int t = threadIdx.x, lane = t & 63, wid = t >> 6;
  float w[64];
#pragma unroll
  for (int k = 0; k < 64; ++k) w[k] = ldf(Wm, k * 64 + lane, m);
  float bias = ldf(bm, lane, m);
  float fn = (float)n;
  float mu1 = stats[lane] / fn;
  float var1 = fmaxf((stats[64 + lane] - mu1 * mu1 * fn) / (fn - 1.0f), 1e-12f);
  float mu2 = stats[128 + lane] / fn;
  float var2 = fmaxf((stats[192 + lane] - mu2 * mu2 * fn) / (fn - 1.0f), 1e-12f);
  float rs1 = rsqrtf(var1), rs2 = rsqrtf(var2);
  long nd = (long)n * DIM;
  float ps = 0.f, pq = 0.f;
  int stride = gridDim.x * 4;
  for (int row = blockIdx.x * 4 + wid; row < n; row += stride) {
    long idx = (long)row * DIM + lane;
    float z1 = (__bfloat162float(H[idx]) - mu1) * rs1;
    float z2 = (__bfloat162float(H[nd + idx]) - mu2) * rs2;
    stf(zout, idx, z1, m);
    stf(zout, nd + idx, z2, m);
    float dz = 0.5f * (z1 + z2);
    float acc = 0.f;
#pragma unroll
    for (int k = 0; k < 64; ++k) acc = fmaf(lane_bcast(dz, k), w[k], acc);
    acc += bias;
    Y[idx] = __float2bfloat16(acc);
    ps += acc;
    pq += acc * acc;
  }
  __shared__ float ssum[4][64], ssq[4][64];
  ssum[wid][lane] = ps;
  ssq[wid][lane] = pq;
  __syncthreads();
  if (t < 64) {
    float a = ssum[0][t] + ssum[1][t] + ssum[2][t] + ssum[3][t];
    float b2 = ssq[0][t] + ssq[1][t] + ssq[2][t] + ssq[3][t];
    atomicAdd(&ystats[t], a);
    atomicAdd(&ystats[64 + t], b2);
  }
}

// ---- head 64x64 matmul + fused column stats (fallback path) ----
__global__ void __launch_bounds__(256) k_mm64s(const bf16* __restrict__ X,
                                               const void* __restrict__ W,
                                               const void* __restrict__ b,
                                               bf16* __restrict__ Y, int n,
                                               const int* __restrict__ mode,
                                               float* __restrict__ stats) {
  int m = *mode;
  int t = threadIdx.x, lane = t & 63, wid = t >> 6;
  float w[64];
#pragma unroll
  for (int k = 0; k < 64; ++k) w[k] = ldf(W, k * 64 + lane, m);
  float bias = ldf(b, lane, m);
  float ps = 0.f, pq = 0.f;
  int stride = gridDim.x * 4;
  for (int row = blockIdx.x * 4 + wid; row < n; row += stride) {
    float a = __bfloat162float(X[(long)row * 64 + lane]);
    float acc = 0.f;
#pragma unroll
    for (int k = 0; k < 64; ++k) acc = fmaf(lane_bcast(a, k), w[k], acc);
    acc += bias;
    Y[(long)row * 64 + lane] = __float2bfloat16(acc);
    ps += acc;
    pq += acc * acc;
  }
  __shared__ float ssum[4][64], ssq[4][64];
  ssum[wid][lane] = ps;
  ssq[wid][lane] = pq;
  __syncthreads();
  if (t < 64) {
    float a = ssum[0][t] + ssum[1][t] + ssum[2][t] + ssum[3][t];
    float b2 = ssq[0][t] + ssq[1][t] + ssq[2][t] + ssq[3][t];
    atomicAdd(&stats[t], a);
    atomicAdd(&stats[64 + t], b2);
  }
}

// ---- sequential standardize (fallback) ----
__global__ void k_z_seq(const bf16* __restrict__ h, const float* __restrict__ stats,
                        void* __restrict__ zout, long zoff, bf16* __restrict__ zacc,
                        int n, int init, const int* __restrict__ mode) {
  int m = *mode;
  int i = blockIdx.x * 256 + threadIdx.x;
  if (i >= n * DIM) return;
  int c = i & 63;
  float fn = (float)n;
  float mu = stats[c] / fn;
  float var = fmaxf((stats[64 + c] - mu * mu * fn) / (fn - 1.0f), 1e-12f);
  float z = (__bfloat162float(h[i]) - mu) * rsqrtf(var);
  stf(zout, zoff + i, z, m);
  float prev = init ? 0.f : __bfloat162float(zacc[i]);
  zacc[i] = __float2bfloat16(prev + 0.5f * z);
}

// ---- BN + relu + 64x40 matmul -> logits ----
__global__ void __launch_bounds__(256) k_head(const bf16* __restrict__ Yv,
                                              const float* __restrict__ s,
                                              const float* __restrict__ sq,
                                              const void* __restrict__ gamma,
                                              const void* __restrict__ beta,
                                              const void* __restrict__ W2,
                                              const void* __restrict__ b2,
                                              void* __restrict__ out, long ooff, int n,
                                              const int* __restrict__ mode) {
  int m = *mode;
  int t = threadIdx.x, lane = t & 63, wid = t >> 6;
  float w[64];
#pragma unroll
  for (int k = 0; k < 64; ++k)
    w[k] = (lane < NCLS_OUT) ? ldf(W2, k * NCLS_OUT + lane, m) : 0.f;
  float bias = (lane < NCLS_OUT) ? ldf(b2, lane, m) : 0.f;
  float fn = (float)n;
  float mu = s[lane] / fn;
  float var = sq[lane] / fn - mu * mu;
  float rstd = rsqrtf(fmaxf(var, 0.f) + 1e-5f);
  float g = ldf(gamma, lane, m);
  float be = ldf(beta, lane, m);
  int stride = gridDim.x * 4;
  for (int row = blockIdx.x * 4 + wid; row < n; row += stride) {
    float yv = __bfloat162float(Yv[(long)row * 64 + lane]);
    float yn = fmaxf((yv - mu) * rstd * g + be, 0.f);
    float acc = bias;
#pragma unroll
    for (int k = 0; k < 64; ++k) acc = fmaf(lane_bcast(yn, k), w[k], acc);
    if (lane < NCLS_OUT) stf(out, ooff + (long)row * NCLS_OUT + lane, acc, m);
  }
}

extern "C" void kernel_launch(void* const* d_in, const int* in_sizes, int n_in,
                              void* d_out, int out_size, void* d_ws, size_t ws_size,
                              hipStream_t stream) {
  const void* feat1 = d_in[0];
  const int* src1 = (const int*)d_in[1];
  const int* dst1 = (const int*)d_in[2];
  const void* feat2 = d_in[3];
  const int* src2 = (const int*)d_in[4];
  const int* dst2 = (const int*)d_in[5];
  const void* W1a = d_in[6];
  const void* b1a = d_in[7];
  const void* W1b = d_in[8];
  const void* b1b = d_in[9];
  const void* W2a = d_in[10];
  const void* b2a = d_in[11];
  const void* W2b = d_in[12];
  const void* b2b = d_in[13];
  const void* Wm1 = d_in[14];
  const void* bm1 = d_in[15];
  const void* gamma = d_in[16];
  const void* beta = d_in[17];
  const void* Wm2 = d_in[18];
  const void* bm2 = d_in[19];

  const int n = in_sizes[0] / DIM;
  const int e1 = in_sizes[1];
  const int e2 = in_sizes[4];
  const int etot = e1 + e2;
  const long nd = (long)n * DIM;
  const int NB = (2 * n + BROWS - 1) >> BSH;

  char* w = (char*)d_ws;
  size_t off = 0;
  auto alloc = [&](size_t bytes) -> void* {
    void* p = w + off;
    off += (bytes + 255) & ~(size_t)255;
    return p;
  };
  int* mode = (int*)alloc(256);
  int* deg = (int*)alloc((size_t)4 * n * 4);
  float* stats = (float*)alloc(512 * 4);
  float* norms = (float*)alloc((size_t)4 * n * 4);
  int* rp = (int*)alloc((size_t)(2 * n + 8) * 4);
  int* bh = (int*)alloc((size_t)(NB + 1) * 4);
  int* bbase = (int*)alloc((size_t)(NB + 1) * 4);
  int* gcur = (int*)alloc((size_t)(NB + 1) * 4);
  int* sb = (int*)alloc((size_t)etot * 4);
  size_t base_off = off;
  bool dual = (ws_size >= base_off + (size_t)5 * nd * 2 + 4096);

  bf16 *P, *Q, *Dz;
  size_t qbytes;
  if (dual) {
    P = (bf16*)alloc((size_t)2 * nd * 2);
    Q = (bf16*)alloc((size_t)2 * nd * 2);
    Dz = (bf16*)alloc((size_t)nd * 2);
    qbytes = (size_t)2 * nd * 2;
  } else {
    P = (bf16*)alloc((size_t)nd * 2);
    Q = (bf16*)alloc((size_t)nd * 2);
    Dz = (bf16*)alloc((size_t)nd * 2);
    qbytes = (size_t)nd * 2;
  }
  // eb (bucket-grouped packed edges) is dead before gmm1 first writes Q, so
  // alias it onto Q when it fits; else take fresh workspace.
  unsigned* eb = ((size_t)etot * 4 <= qbytes) ? (unsigned*)Q
                                              : (unsigned*)alloc((size_t)etot * 4);

  const float* nd1 = norms;
  const float* nd2 = norms + n;
  const float* ns1 = norms + 2 * n;
  const float* ns2 = norms + 3 * n;

  int gND = (int)((nd + 255) / 256);
  int g2ND8 = (int)((2 * nd / 8 + 255) / 256);
  int gBIN = (etot + BIN_CHUNK - 1) / BIN_CHUNK;
  const int gGMM = 4096;

  hipMemsetAsync(deg + 2 * n, 0, (size_t)2 * n * 4, stream);
  hipMemsetAsync(stats, 0, 512 * 4, stream);
  hipMemsetAsync(bh, 0, (size_t)NB * 4, stream);

  k_detect<<<1, 1024, 0, stream>>>((const unsigned int*)feat1, 8192, mode);

  // fused out-degree + bucket histogram (one edge-list pass), then bucket sort
  k_deg_hist<<<256, 256, (size_t)NB * 4, stream>>>(src1, dst1, src2, dst2, deg, bh,
                                                   n, e1, etot, NB);
  k_bscan<<<1, 256, 0, stream>>>(bh, bbase, gcur, rp, NB, etot, 2 * n);
  k_bin<<<gBIN, 256, (size_t)2 * NB * 4, stream>>>(src1, dst1, src2, dst2, gcur, eb,
                                                   n, e1, etot, NB);
  k_fine<<<NB, 256, 0, stream>>>(eb, bbase, rp, deg, norms, sb, 2 * n, NB);

  if (dual) {
    k_scale_all<<<g2ND8, 256, 0, stream>>>(feat1, feat2, norms, P, n, mode);
    k_gmm<<<gGMM, 256, 0, stream>>>(P, rp, sb, W1a, b1a, W2a, b2a, nd1, nd2, ns1, ns2,
                                    Q, n, 1, mode, 1, 0, (float*)nullptr);
    k_gmm<<<gGMM, 256, 0, stream>>>(Q, rp, sb, W1b, b1b, W2b, b2b, nd1, nd2,
                                    (const float*)nullptr, (const float*)nullptr,
                                    P, n, 0, mode, 1, 0, stats);
    // fused standardize + head matmul (Dz in registers)
    k_zmm<<<512, 256, 0, stream>>>(P, stats, d_out, Wm1, bm1, Q, n, mode, stats + 256);
  } else {
    // graph 1
    k_scale_one<<<gND, 256, 0, stream>>>(feat1, ns1, P, (int)nd, mode);
    k_gmm<<<gGMM, 256, 0, stream>>>(P, rp, sb, W1a, b1a, W1a, b1a, nd1, nd1, ns1, ns1,
                                    Q, n, 1, mode, 0, 0, (float*)nullptr);
    k_gmm<<<gGMM, 256, 0, stream>>>(Q, rp, sb, W1b, b1b, W1b, b1b, nd1, nd1,
                                    (const float*)nullptr, (const float*)nullptr,
                                    P, n, 0, mode, 0, 0, stats);
    k_z_seq<<<gND, 256, 0, stream>>>(P, stats, d_out, 0L, Dz, n, 1, mode);
    // graph 2
    k_scale_one<<<gND, 256, 0, stream>>>(feat2, ns2, P, (int)nd, mode);
    k_gmm<<<gGMM, 256, 0, stream>>>(P, rp, sb, W2a, b2a, W2a, b2a, nd2, nd2, ns2, ns2,
                                    Q, n, 1, mode, 0, 1, (float*)nullptr);
    k_gmm<<<gGMM, 256, 0, stream>>>(Q, rp, sb, W2b, b2b, W2b, b2b, nd2, nd2,
                                    (const float*)nullptr, (const float*)nullptr,
                                    P, n, 0, mode, 0, 1, stats + 128);
    k_z_seq<<<gND, 256, 0, stream>>>(P, stats + 128, d_out, nd, Dz, n, 0, mode);
    k_mm64s<<<512, 256, 0, stream>>>(Dz, Wm1, bm1, Q, n, mode, stats + 256);
  }

  // BN ; relu ; @Wm2+bm2
  k_head<<<512, 256, 0, stream>>>(Q, stats + 256, stats + 320, gamma, beta, Wm2, bm2,
                                  d_out, 2 * nd, n, mode);
}